// Round 1
// baseline (566.536 us; speedup 1.0000x reference)
//
#include <hip/hip_runtime.h>

#define BATCH 2048
#define T     128
#define CIN   2
#define COUT  16
#define H     232
#define G3    696          // 3*H gates
#define NT    44           // N tiles of 16 gates (704 padded)
#define NS    9            // K slices of 32 (h: 0..231, x tail 232..247 for rz, x slice 8 for n)
#define RZ_TILES 29        // tiles [0,29): r/z (sigmoid-combined); [29,44): n
#define RPB   16           // batch rows per block
#define NBLK  (BATCH/RPB)  // 128
#define NTHR  512          // 8 waves

typedef _Float16 half8 __attribute__((ext_vector_type(8)));
typedef float  floatx4 __attribute__((ext_vector_type(4)));

// packed fp16 weights, fragment-contiguous: [tile][slice][lane][8]
__device__ __align__(16) _Float16 g_packedW[NT * NS * 64 * 8];

// B-fragment layout assumed: lane holds col n = lane&15, k = (lane>>4)*8 + i (8 contiguous)
__global__ void pack_w_kernel(const float* __restrict__ w_ih,
                              const float* __restrict__ w_hh) {
  int tile = blockIdx.x, slice = blockIdx.y, lane = threadIdx.x;
  int g = tile * 16 + (lane & 15);
  int kbase = slice * 32 + ((lane >> 4) << 3);
  half8 v = {};
  #pragma unroll
  for (int i = 0; i < 8; ++i) {
    int k = kbase + i;
    float f = 0.f;
    if (g < G3) {
      if (k < H) {
        f = w_hh[g * H + k];                        // recurrent weights
      } else if (k < H + COUT) {
        if (tile < RZ_TILES) f = w_ih[g * COUT + (k - H)];   // x folded into K tail (rz only)
      } else if (k >= 256 && k < 256 + COUT) {
        if (tile >= RZ_TILES) f = w_ih[g * COUT + (k - 256)]; // separate in_ slice for n-gates
      }
    }
    v[i] = (_Float16)f;
  }
  *(half8*)&g_packedW[((tile * NS + slice) * 64 + lane) * 8] = v;
}

// LDS A-fragment index with XOR swizzle (2-way max bank aliasing on ds_read_b128)
__device__ __forceinline__ int haidx(int s, int r, int kp) {
  return (s * 16 + r) * 32 + ((((kp >> 3) ^ (r & 3))) << 3) + (kp & 7);
}

__device__ __forceinline__ float sigmoid_f(float x) {
  return 1.f / (1.f + __expf(-x));
}

__global__ __launch_bounds__(NTHR) void st_gru_kernel(
    const float* __restrict__ X, const float* __restrict__ conv_w,
    const float* __restrict__ conv_b, const float* __restrict__ b_ih,
    const float* __restrict__ b_hh, float* __restrict__ out) {
  __shared__ float Xs[RPB * T * CIN];                 // 16 KB
  __shared__ __align__(16) _Float16 hA[NS * 16 * 32]; // 9 KB  (A frags: h + x + pads)
  __shared__ float act_rz[RPB * 2 * H];               // 29.7 KB (sigmoid(r), sigmoid(z))
  __shared__ float hnb[RPB * H];                      // 14.8 KB (hn + b_hh)
  __shared__ float inb[RPB * H];                      // 14.8 KB (in + b_ih)
  __shared__ float h32[RPB * H];                      // 14.8 KB fp32 master h
  __shared__ float bih[G3], bhh[G3];
  __shared__ float cw[COUT * CIN * 3], cb[COUT];

  const int tid = threadIdx.x;
  const int lane = tid & 63;
  const int wave = tid >> 6;
  const int blk = blockIdx.x;

  for (int i = tid; i < RPB * T * CIN; i += NTHR) Xs[i] = X[blk * RPB * T * CIN + i];
  for (int i = tid; i < G3; i += NTHR) { bih[i] = b_ih[i]; bhh[i] = b_hh[i]; }
  if (tid < COUT * CIN * 3) cw[tid] = conv_w[tid];
  if (tid < COUT) cb[tid] = conv_b[tid];
  for (int i = tid; i < NS * 16 * 32; i += NTHR) hA[i] = (_Float16)0.f;  // h=0 + pads=0
  for (int i = tid; i < RPB * H; i += NTHR) h32[i] = 0.f;
  __syncthreads();

  // wave -> N-tile range: waves 0-3 own 6 tiles, waves 4-7 own 5 tiles (44 total)
  int tstart, tcount;
  if (wave < 4) { tstart = wave * 6; tcount = 6; }
  else          { tstart = 24 + (wave - 4) * 5; tcount = 5; }

  const int r_a = lane & 15;   // A row / C col index
  const int ch4 = lane >> 4;   // k-chunk / C row group

  for (int t = 0; t < T; ++t) {
    // ---- phase X: conv1d(k=3,pad=1)+ReLU -> x_t into hA (slice7 tail + slice8 head)
    if (tid < RPB * COUT) {
      int r = tid >> 4, c = tid & 15;
      float a = cb[c];
      #pragma unroll
      for (int ci = 0; ci < CIN; ++ci)
        #pragma unroll
        for (int dk = 0; dk < 3; ++dk) {
          int tt = t + dk - 1;
          if (tt >= 0 && tt < T) a += Xs[r * (T * CIN) + tt * CIN + ci] * cw[c * 6 + ci * 3 + dk];
        }
      _Float16 hv = (_Float16)fmaxf(a, 0.f);
      hA[haidx(7, r, 8 + c)] = hv;   // k = 232+c (combined pass for r/z)
      hA[haidx(8, r, c)] = hv;       // k = 256+c (in_ pass for n)
    }
    __syncthreads();

    // ---- MFMA phase: gates[16 rows x 704] = [h,x] @ W^T
    half8 afrag[NS];
    #pragma unroll
    for (int s = 0; s < NS; ++s)
      afrag[s] = *(const half8*)&hA[(s * 16 + r_a) * 32 + ((ch4 ^ (r_a & 3)) << 3)];

    for (int ti = 0; ti < tcount; ++ti) {
      int tile = tstart + ti;
      const half8* wp = (const half8*)&g_packedW[(tile * NS) * 64 * 8 + lane * 8];
      int g = tile * 16 + r_a;
      if (tile < RZ_TILES) {
        floatx4 acc = {0.f, 0.f, 0.f, 0.f};
        #pragma unroll
        for (int s = 0; s < 8; ++s)
          acc = __builtin_amdgcn_mfma_f32_16x16x32_f16(afrag[s], wp[s * 64], acc, 0, 0, 0);
        float bs = bih[g] + bhh[g];
        #pragma unroll
        for (int i = 0; i < 4; ++i) {
          int row = ch4 * 4 + i;                       // C: col=lane&15, row=(lane>>4)*4+i
          act_rz[row * (2 * H) + g] = sigmoid_f(acc[i] + bs);
        }
      } else {
        floatx4 acch = {0.f, 0.f, 0.f, 0.f}, accx = {0.f, 0.f, 0.f, 0.f};
        #pragma unroll
        for (int s = 0; s < 8; ++s)
          acch = __builtin_amdgcn_mfma_f32_16x16x32_f16(afrag[s], wp[s * 64], acch, 0, 0, 0);
        accx = __builtin_amdgcn_mfma_f32_16x16x32_f16(afrag[8], wp[8 * 64], accx, 0, 0, 0);
        if (g < G3) {
          int j = g - 2 * H;
          float bh_ = bhh[g], bi_ = bih[g];
          #pragma unroll
          for (int i = 0; i < 4; ++i) {
            int row = ch4 * 4 + i;
            hnb[row * H + j] = acch[i] + bh_;
            inb[row * H + j] = accx[i] + bi_;
          }
        }
      }
    }
    __syncthreads();

    // ---- h update: n = tanh(in + r*hn); h' = (1-z)*n + z*h
    for (int idx = tid; idx < RPB * H; idx += NTHR) {
      int row = idx / H, j = idx - row * H;
      float rr = act_rz[row * (2 * H) + j];
      float zz = act_rz[row * (2 * H) + H + j];
      float pre = inb[idx] + rr * hnb[idx];
      float e = __expf(2.f * pre);
      float n = 1.f - 2.f / (e + 1.f);                 // tanh, inf-safe
      float hnew = zz * h32[idx] + (1.f - zz) * n;
      h32[idx] = hnew;
      hA[haidx(j >> 5, row, j & 31)] = (_Float16)hnew; // fp16 copy for next step's MFMA
    }
    // no barrier needed: next X-phase touches disjoint hA region; barrier after X covers reads
  }

  for (int idx = tid; idx < RPB * H; idx += NTHR)
    out[blk * RPB * H + idx] = h32[idx];
}

extern "C" void kernel_launch(void* const* d_in, const int* in_sizes, int n_in,
                              void* d_out, int out_size, void* d_ws, size_t ws_size,
                              hipStream_t stream) {
  const float* X      = (const float*)d_in[0];
  const float* conv_w = (const float*)d_in[1];
  const float* conv_b = (const float*)d_in[2];
  const float* w_ih   = (const float*)d_in[3];
  const float* w_hh   = (const float*)d_in[4];
  const float* b_ih   = (const float*)d_in[5];
  const float* b_hh   = (const float*)d_in[6];
  float* out = (float*)d_out;

  pack_w_kernel<<<dim3(NT, NS), 64, 0, stream>>>(w_ih, w_hh);
  st_gru_kernel<<<NBLK, NTHR, 0, stream>>>(X, conv_w, conv_b, b_ih, b_hh, out);
}

// Round 2
// 415.648 us; speedup vs baseline: 1.3630x; 1.3630x over previous
//
#include <hip/hip_runtime.h>

#define BATCH 2048
#define T     128
#define CIN   2
#define COUT  16
#define H     232
#define RPB   8                 // batch rows per block
#define NBLK  (BATCH/RPB)       // 256 blocks -> 1 per CU
#define NTHR  512               // 8 waves
#define NGRP  15                // j-groups of 16 (gates padded 232->240 per gate-type)
#define NT2   48                // tiles: r=0..14, z=15..29, n=30..44, 45..47 zero pad
#define NS    9                 // K slices of 32 (h 0..231 + x tail; slice 8 = x for n)
#define HROW  272               // hA row stride in halves (544B, breaks 128B bank cycle)

typedef _Float16 half8 __attribute__((ext_vector_type(8)));
typedef float  floatx4 __attribute__((ext_vector_type(4)));

#define MFMA __builtin_amdgcn_mfma_f32_16x16x32_f16

// packed fp16 weights, fragment-contiguous: [tile][slice][lane][8]
__device__ __align__(16) _Float16 g_packedW[NT2 * NS * 64 * 8];

__global__ void pack_w_kernel(const float* __restrict__ w_ih,
                              const float* __restrict__ w_hh) {
  int tile = blockIdx.x, slice = blockIdx.y, lane = threadIdx.x;
  int grp = tile / NGRP;                       // 0=r,1=z,2=n (3=dummy)
  int j   = (tile % NGRP) * 16 + (lane & 15);  // gate column within group
  int g   = grp * H + j;                       // original gate row
  bool valid = (tile < 3 * NGRP) && (j < H);
  half8 v = {};
  if (valid) {
#pragma unroll
    for (int i = 0; i < 8; ++i) {
      int k = slice * 32 + ((lane >> 4) << 3) + i;
      float f = 0.f;
      if (slice < 8) {
        if (k < H) f = w_hh[g * H + k];                         // recurrent part
        else if (k < H + COUT && grp < 2) f = w_ih[g * COUT + (k - H)];  // x folded (r,z)
      } else {
        int xk = k - 256;                                       // slice 8: x for n-gates
        if (xk >= 0 && xk < COUT && grp == 2) f = w_ih[g * COUT + xk];
      }
      v[i] = (_Float16)f;
    }
  }
  *(half8*)&g_packedW[((tile * NS + slice) * 64 + lane) * 8] = v;
}

__device__ __forceinline__ float sigmoid_f(float x) {
  return __fdividef(1.f, 1.f + __expf(-x));
}

__global__ __launch_bounds__(NTHR) void st_gru_kernel(
    const float* __restrict__ X,
    const float* __restrict__ conv_w, const float* __restrict__ conv_b,
    const float* __restrict__ b_ih, const float* __restrict__ b_hh,
    float* __restrict__ out) {

  __shared__ __align__(64) _Float16 hAflat[2 * RPB * HROW];  // ping-pong fp16 h, swizzled
  __shared__ __align__(64) _Float16 Xemb[T * RPB * 16];      // conv output, all t (32 KB)
  __shared__ __align__(64) float zbuf[16];                   // stays zero after init
  __shared__ float cw[COUT * CIN * 3 + COUT];                // conv w + b

  const int tid  = threadIdx.x;
  const int lane = tid & 63;
  const int wave = tid >> 6;
  const int r_a  = lane & 15;   // A row / C col (gate j within group)
  const int ch4  = lane >> 4;   // k-chunk / C row group
  const int blk  = blockIdx.x;

  for (int i = tid; i < 2 * RPB * HROW; i += NTHR) hAflat[i] = (_Float16)0;
  if (tid < 16) zbuf[tid] = 0.f;
  if (tid < COUT * CIN * 3) cw[tid] = conv_w[tid];
  if (tid < COUT) cw[96 + tid] = conv_b[tid];
  __syncthreads();

  // ---- conv1d(2->16,k=3,pad=1)+ReLU for ALL t upfront -> Xemb (fp16)
  for (int p = tid; p < RPB * T; p += NTHR) {
    int r = p >> 7, t = p & (T - 1);
    const float* xr = X + (size_t)(blk * RPB + r) * (T * CIN);
    float x0[3], x1[3];
#pragma unroll
    for (int d = 0; d < 3; ++d) {
      int tt = t + d - 1;
      bool ok = (unsigned)tt < (unsigned)T;
      x0[d] = ok ? xr[tt * 2] : 0.f;
      x1[d] = ok ? xr[tt * 2 + 1] : 0.f;
    }
    half8 lo, hi;
#pragma unroll
    for (int c = 0; c < COUT; ++c) {
      float a = cw[96 + c];
#pragma unroll
      for (int d = 0; d < 3; ++d)
        a += x0[d] * cw[c * 6 + d] + x1[d] * cw[c * 6 + 3 + d];
      _Float16 hv = (_Float16)fmaxf(a, 0.f);
      if (c < 8) lo[c] = hv; else hi[c - 8] = hv;
    }
    *(half8*)&Xemb[(t * RPB + r) * 16] = lo;
    *(half8*)&Xemb[(t * RPB + r) * 16 + 8] = hi;
  }

  // ---- persistent weight fragments in VGPRs (each wave owns 2 gate-triples)
  const int gi0 = wave * 2, gi1 = wave * 2 + 1;
  const bool g1ok = (gi1 < NGRP);
  const int tr0 = gi0, tz0 = gi0 + NGRP, tn0 = gi0 + 2 * NGRP;
  const int tr1 = g1ok ? gi1 : 45, tz1 = g1ok ? gi1 + NGRP : 46, tn1 = g1ok ? gi1 + 2 * NGRP : 47;
  const half8* Wp = (const half8*)g_packedW;
  half8 wr0[8], wz0[8], wr1[8], wz1[8], wn0[9], wn1[9];
#pragma unroll
  for (int s = 0; s < 8; ++s) {
    wr0[s] = Wp[(tr0 * NS + s) * 64 + lane];
    wz0[s] = Wp[(tz0 * NS + s) * 64 + lane];
    wr1[s] = Wp[(tr1 * NS + s) * 64 + lane];
    wz1[s] = Wp[(tz1 * NS + s) * 64 + lane];
  }
#pragma unroll
  for (int s = 0; s < 9; ++s) {
    wn0[s] = Wp[(tn0 * NS + s) * 64 + lane];
    wn1[s] = Wp[(tn1 * NS + s) * 64 + lane];
  }

  const int j0 = gi0 * 16 + r_a, j1 = gi1 * 16 + r_a;
  float bsr0 = 0.f, bsz0 = 0.f, bin0 = 0.f, bhn0 = 0.f;
  float bsr1 = 0.f, bsz1 = 0.f, bin1 = 0.f, bhn1 = 0.f;
  if (j0 < H) {
    bsr0 = b_ih[j0] + b_hh[j0];
    bsz0 = b_ih[H + j0] + b_hh[H + j0];
    bin0 = b_ih[2 * H + j0]; bhn0 = b_hh[2 * H + j0];
  }
  if (g1ok && j1 < H) {
    bsr1 = b_ih[j1] + b_hh[j1];
    bsz1 = b_ih[H + j1] + b_hh[H + j1];
    bin1 = b_ih[2 * H + j1]; bhn1 = b_hh[2 * H + j1];
  }

  float h0[4] = {0.f, 0.f, 0.f, 0.f};
  float h1[4] = {0.f, 0.f, 0.f, 0.f};

  const bool rowok = (r_a < RPB);
  const int  rr    = rowok ? r_a : 0;
  const int  swz   = rr & 3;
  const _Float16* zp = (const _Float16*)zbuf;

  __syncthreads();

#pragma unroll 2
  for (int t = 0; t < T; ++t) {
    const _Float16* rb = hAflat + (t & 1) * (RPB * HROW);
    _Float16* wb = hAflat + ((t & 1) ^ 1) * (RPB * HROW);
    const _Float16* xrow = Xemb + (t * RPB + rr) * 16;

    // A fragments: slices 0..6 = h[0..223]; slice7rz = h-tail+x; slice7n = h-tail; slice8 = x
    half8 A[7], A7rz, A7n, A8;
#pragma unroll
    for (int s = 0; s < 7; ++s) {
      const _Float16* p = rowok ? rb + rr * HROW + s * 32 + ((ch4 ^ swz) << 3) : zp;
      A[s] = *(const half8*)p;
    }
    {
      const _Float16* ph = rb + rr * HROW + 224 + (swz << 3);
      const _Float16* p = !rowok ? zp
                        : (ch4 == 0 ? ph : (ch4 == 3 ? zp : xrow + (ch4 - 1) * 8));
      A7rz = *(const half8*)p;
      const _Float16* pn = (rowok && ch4 == 0) ? ph : zp;
      A7n = *(const half8*)pn;
      const _Float16* p8 = (rowok && ch4 < 2) ? xrow + ch4 * 8 : zp;
      A8 = *(const half8*)p8;
    }

    floatx4 ra0 = {}, za0 = {}, na0 = {}, xa0 = {};
    floatx4 ra1 = {}, za1 = {}, na1 = {}, xa1 = {};
#pragma unroll
    for (int s = 0; s < 7; ++s) {
      ra0 = MFMA(A[s], wr0[s], ra0, 0, 0, 0);
      za0 = MFMA(A[s], wz0[s], za0, 0, 0, 0);
      na0 = MFMA(A[s], wn0[s], na0, 0, 0, 0);
      ra1 = MFMA(A[s], wr1[s], ra1, 0, 0, 0);
      za1 = MFMA(A[s], wz1[s], za1, 0, 0, 0);
      na1 = MFMA(A[s], wn1[s], na1, 0, 0, 0);
    }
    ra0 = MFMA(A7rz, wr0[7], ra0, 0, 0, 0);
    za0 = MFMA(A7rz, wz0[7], za0, 0, 0, 0);
    ra1 = MFMA(A7rz, wr1[7], ra1, 0, 0, 0);
    za1 = MFMA(A7rz, wz1[7], za1, 0, 0, 0);
    na0 = MFMA(A7n, wn0[7], na0, 0, 0, 0);
    na1 = MFMA(A7n, wn1[7], na1, 0, 0, 0);
    xa0 = MFMA(A8, wn0[8], xa0, 0, 0, 0);
    xa1 = MFMA(A8, wn1[8], xa1, 0, 0, 0);

    // in-register GRU update (rows live in ch4<2 lanes), write fp16 h to other buffer
    if (ch4 < 2) {
#pragma unroll
      for (int i = 0; i < 4; ++i) {
        int row = ch4 * 4 + i;
        {
          float r = sigmoid_f(ra0[i] + bsr0);
          float z = sigmoid_f(za0[i] + bsz0);
          float pre = xa0[i] + bin0 + r * (na0[i] + bhn0);
          float e = __expf(2.f * pre);
          float n = 1.f - __fdividef(2.f, e + 1.f);
          h0[i] = z * h0[i] + (1.f - z) * n;
          int pos = (j0 & ~31) | ((((j0 >> 3) & 3) ^ (row & 3)) << 3) | (j0 & 7);
          wb[row * HROW + pos] = (_Float16)h0[i];
        }
        {
          float r = sigmoid_f(ra1[i] + bsr1);
          float z = sigmoid_f(za1[i] + bsz1);
          float pre = xa1[i] + bin1 + r * (na1[i] + bhn1);
          float e = __expf(2.f * pre);
          float n = 1.f - __fdividef(2.f, e + 1.f);
          h1[i] = z * h1[i] + (1.f - z) * n;
          if (g1ok) {
            int pos = (j1 & ~31) | ((((j1 >> 3) & 3) ^ (row & 3)) << 3) | (j1 & 7);
            wb[row * HROW + pos] = (_Float16)h1[i];
          }
        }
      }
    }
    __syncthreads();
  }

  if (ch4 < 2) {
#pragma unroll
    for (int i = 0; i < 4; ++i) {
      int row = ch4 * 4 + i;
      if (j0 < H) out[(size_t)(blk * RPB + row) * H + j0] = h0[i];
      if (g1ok && j1 < H) out[(size_t)(blk * RPB + row) * H + j1] = h1[i];
    }
  }
}

extern "C" void kernel_launch(void* const* d_in, const int* in_sizes, int n_in,
                              void* d_out, int out_size, void* d_ws, size_t ws_size,
                              hipStream_t stream) {
  const float* X      = (const float*)d_in[0];
  const float* conv_w = (const float*)d_in[1];
  const float* conv_b = (const float*)d_in[2];
  const float* w_ih   = (const float*)d_in[3];
  const float* w_hh   = (const float*)d_in[4];
  const float* b_ih   = (const float*)d_in[5];
  const float* b_hh   = (const float*)d_in[6];
  float* out = (float*)d_out;

  pack_w_kernel<<<dim3(NT2, NS), 64, 0, stream>>>(w_ih, w_hh);
  st_gru_kernel<<<NBLK, NTHR, 0, stream>>>(X, conv_w, conv_b, b_ih, b_hh, out);
}

// Round 3
// 324.360 us; speedup vs baseline: 1.7466x; 1.2814x over previous
//
#include <hip/hip_runtime.h>

#define BATCH 2048
#define T     128
#define CIN   2
#define COUT  16
#define H     232
#define RPB   8                 // batch rows per block
#define NBLK  (BATCH/RPB)       // 256 blocks -> 1 per CU
#define NTHR  512               // 8 waves, 2/SIMD
#define NGRP  15                // j-groups of 16 (232 -> 15*16=240 padded)
#define NT2   48                // tiles: r=0..14, z=15..29, n=30..44, 45..47 zero pad
#define NS    9                 // K slices of 32
#define HROW  272               // hA row stride in halves (544B, breaks bank cycle)

// dynamic LDS carve (bytes)
#define OFF_HA   0
#define SZ_HA    (2 * RPB * HROW * 2)          // 8704: ping-pong fp16 h
#define OFF_XE   (OFF_HA + SZ_HA)
#define SZ_XE    (T * RPB * 16 * 2)            // 32768: conv output all t
#define OFF_WL   (OFF_XE + SZ_XE)
#define SZ_WL    (8 * 10 * 64 * 8 * 2)         // 81920: per-wave z s0..3 + xn frags
#define OFF_CW   (OFF_WL + SZ_WL)
#define SZ_CW    512                            // conv w+b
#define SMEM_BYTES (OFF_CW + SZ_CW)            // 123904

typedef _Float16 half8 __attribute__((ext_vector_type(8)));
typedef float  floatx4 __attribute__((ext_vector_type(4)));

#define MFMA __builtin_amdgcn_mfma_f32_16x16x32_f16

// packed fp16 weights, fragment-contiguous: [tile][slice][lane][8]
__device__ __align__(16) _Float16 g_packedW[NT2 * NS * 64 * 8];

__global__ void pack_w_kernel(const float* __restrict__ w_ih,
                              const float* __restrict__ w_hh) {
  int tile = blockIdx.x, slice = blockIdx.y, lane = threadIdx.x;
  int grp = tile / NGRP;                       // 0=r,1=z,2=n (3=dummy)
  int j   = (tile % NGRP) * 16 + (lane & 15);  // gate column within group
  int g   = grp * H + j;                       // original gate row
  bool valid = (tile < 3 * NGRP) && (j < H);
  half8 v = {};
  if (valid) {
#pragma unroll
    for (int i = 0; i < 8; ++i) {
      int k = slice * 32 + ((lane >> 4) << 3) + i;
      float f = 0.f;
      if (slice < 8) {
        if (k < H) f = w_hh[g * H + k];                                  // recurrent
        else if (k < H + COUT && grp < 2) f = w_ih[g * COUT + (k - H)];  // x folded (r,z)
      } else {
        int xk = k - 256;                                                // slice 8: x for n
        if (xk >= 0 && xk < COUT && grp == 2) f = w_ih[g * COUT + xk];
      }
      v[i] = (_Float16)f;
    }
  }
  *(half8*)&g_packedW[((tile * NS + slice) * 64 + lane) * 8] = v;
}

__device__ __forceinline__ float sigmoid_f(float x) {
  return __fdividef(1.f, 1.f + __expf(-x));
}

__global__ __launch_bounds__(NTHR, 2) void st_gru_kernel(
    const float* __restrict__ X,
    const float* __restrict__ conv_w, const float* __restrict__ conv_b,
    const float* __restrict__ b_ih, const float* __restrict__ b_hh,
    float* __restrict__ out) {

  extern __shared__ __align__(16) char smem[];
  _Float16* hAflat = (_Float16*)(smem + OFF_HA);
  _Float16* Xemb   = (_Float16*)(smem + OFF_XE);
  _Float16* wLDS   = (_Float16*)(smem + OFF_WL);
  float*    cwp    = (float*)(smem + OFF_CW);

  const int tid  = threadIdx.x;
  const int lane = tid & 63;
  const int wave = tid >> 6;
  const int r_a  = lane & 15;   // A row / C col
  const int ch4  = lane >> 4;   // k-chunk / C row group
  const int blk  = blockIdx.x;
  const int rr   = r_a & 7;     // batch row this lane reads (dup for r_a>=8, harmless)
  const int swz  = rr & 3;

  for (int i = tid; i < 2 * RPB * HROW; i += NTHR) hAflat[i] = (_Float16)0;
  if (tid < COUT * CIN * 3) cwp[tid] = conv_w[tid];
  if (tid < COUT) cwp[96 + tid] = conv_b[tid];
  __syncthreads();

  // ---- conv1d(2->16,k=3,pad=1)+ReLU for ALL t upfront -> Xemb (fp16)
  for (int p = tid; p < RPB * T; p += NTHR) {
    int r = p >> 7, t = p & (T - 1);
    const float* xr = X + (size_t)(blk * RPB + r) * (T * CIN);
    float x0[3], x1[3];
#pragma unroll
    for (int d = 0; d < 3; ++d) {
      int tt = t + d - 1;
      bool ok = (unsigned)tt < (unsigned)T;
      x0[d] = ok ? xr[tt * 2] : 0.f;
      x1[d] = ok ? xr[tt * 2 + 1] : 0.f;
    }
    half8 lo, hi;
#pragma unroll
    for (int c = 0; c < COUT; ++c) {
      float a = cwp[96 + c];
#pragma unroll
      for (int d = 0; d < 3; ++d)
        a += x0[d] * cwp[c * 6 + d] + x1[d] * cwp[c * 6 + 3 + d];
      _Float16 hv = (_Float16)fmaxf(a, 0.f);
      if (c < 8) lo[c] = hv; else hi[c - 8] = hv;
    }
    *(half8*)&Xemb[(t * RPB + r) * 16] = lo;
    *(half8*)&Xemb[(t * RPB + r) * 16 + 8] = hi;
  }

  // ---- per-wave tiles (2 gate-triples each)
  const int gi0 = wave * 2, gi1 = wave * 2 + 1;
  const bool g1ok = (gi1 < NGRP);
  const int tr0 = gi0, tz0 = gi0 + NGRP, tn0 = gi0 + 2 * NGRP;
  const int tr1 = g1ok ? gi1 : 45, tz1 = g1ok ? gi1 + NGRP : 46, tn1 = g1ok ? gi1 + 2 * NGRP : 47;
  const half8* Wp = (const half8*)g_packedW;

  // LDS-staged frags: z s0..3 of both tiles (0..7), x-slice of n for both (8,9)
  half8* myz = (half8*)(wLDS + wave * (10 * 64 * 8));
#pragma unroll
  for (int f = 0; f < 4; ++f) myz[f * 64 + lane] = Wp[(tz0 * NS + f) * 64 + lane];
#pragma unroll
  for (int f = 0; f < 4; ++f) myz[(4 + f) * 64 + lane] = Wp[(tz1 * NS + f) * 64 + lane];
  myz[8 * 64 + lane] = Wp[(tn0 * NS + 8) * 64 + lane];
  myz[9 * 64 + lane] = Wp[(tn1 * NS + 8) * 64 + lane];

  // VGPR-resident frags: r s0..7, n s0..7, z s4..7
  half8 wr0[8], wr1[8], wn0[8], wn1[8], wzh0[4], wzh1[4];
#pragma unroll
  for (int s = 0; s < 8; ++s) {
    wr0[s] = Wp[(tr0 * NS + s) * 64 + lane];
    wr1[s] = Wp[(tr1 * NS + s) * 64 + lane];
    wn0[s] = Wp[(tn0 * NS + s) * 64 + lane];
    wn1[s] = Wp[(tn1 * NS + s) * 64 + lane];
  }
#pragma unroll
  for (int s = 0; s < 4; ++s) {
    wzh0[s] = Wp[(tz0 * NS + 4 + s) * 64 + lane];
    wzh1[s] = Wp[(tz1 * NS + 4 + s) * 64 + lane];
  }

  const int j0 = gi0 * 16 + r_a, j1 = gi1 * 16 + r_a;
  float bsr0 = 0.f, bsz0 = 0.f, bin0 = 0.f, bhn0 = 0.f;
  float bsr1 = 0.f, bsz1 = 0.f, bin1 = 0.f, bhn1 = 0.f;
  if (j0 < H) {
    bsr0 = b_ih[j0] + b_hh[j0];
    bsz0 = b_ih[H + j0] + b_hh[H + j0];
    bin0 = b_ih[2 * H + j0]; bhn0 = b_hh[2 * H + j0];
  }
  if (g1ok && j1 < H) {
    bsr1 = b_ih[j1] + b_hh[j1];
    bsz1 = b_ih[H + j1] + b_hh[H + j1];
    bin1 = b_ih[2 * H + j1]; bhn1 = b_hh[2 * H + j1];
  }

  float h0[4] = {0.f, 0.f, 0.f, 0.f};
  float h1[4] = {0.f, 0.f, 0.f, 0.f};

  __syncthreads();

  const int abase = rr * HROW + ((ch4 ^ swz) << 3);   // A-frag lane offset (halves)

  for (int t = 0; t < T; ++t) {
    const _Float16* rb = hAflat + (t & 1) * (RPB * HROW);
    _Float16* wb = hAflat + ((t & 1) ^ 1) * (RPB * HROW);

    half8 xlo = *(const half8*)&Xemb[(t * RPB + rr) * 16];
    half8 xhi = *(const half8*)&Xemb[(t * RPB + rr) * 16 + 8];

    floatx4 ra0 = {}, za0 = {}, na0 = {}, ra1 = {}, za1 = {}, na1 = {};
#pragma unroll
    for (int s = 0; s < 4; ++s) {          // z weights from LDS
      half8 a = *(const half8*)&rb[abase + s * 32];
      half8 z0f = myz[s * 64 + lane];
      half8 z1f = myz[(4 + s) * 64 + lane];
      ra0 = MFMA(a, wr0[s], ra0, 0, 0, 0);
      za0 = MFMA(a, z0f, za0, 0, 0, 0);
      na0 = MFMA(a, wn0[s], na0, 0, 0, 0);
      ra1 = MFMA(a, wr1[s], ra1, 0, 0, 0);
      za1 = MFMA(a, z1f, za1, 0, 0, 0);
      na1 = MFMA(a, wn1[s], na1, 0, 0, 0);
    }
#pragma unroll
    for (int s = 4; s < 7; ++s) {          // z weights from VGPR
      half8 a = *(const half8*)&rb[abase + s * 32];
      ra0 = MFMA(a, wr0[s], ra0, 0, 0, 0);
      za0 = MFMA(a, wzh0[s - 4], za0, 0, 0, 0);
      na0 = MFMA(a, wn0[s], na0, 0, 0, 0);
      ra1 = MFMA(a, wr1[s], ra1, 0, 0, 0);
      za1 = MFMA(a, wzh1[s - 4], za1, 0, 0, 0);
      na1 = MFMA(a, wn1[s], na1, 0, 0, 0);
    }
    // s=7: h-tail (ch4==0) + x (ch4 1,2). n/x weight tails are zero -> masks garbage lanes.
    {
      half8 ht = *(const half8*)&rb[rr * HROW + 224 + (swz << 3)];
      half8 a7 = (ch4 == 0) ? ht : ((ch4 == 1) ? xlo : xhi);
      ra0 = MFMA(a7, wr0[7], ra0, 0, 0, 0);
      za0 = MFMA(a7, wzh0[3], za0, 0, 0, 0);
      na0 = MFMA(a7, wn0[7], na0, 0, 0, 0);
      ra1 = MFMA(a7, wr1[7], ra1, 0, 0, 0);
      za1 = MFMA(a7, wzh1[3], za1, 0, 0, 0);
      na1 = MFMA(a7, wn1[7], na1, 0, 0, 0);
    }
    // s=8: x projection for n-gates (weights zero beyond xk<16)
    floatx4 xa0 = {}, xa1 = {};
    {
      half8 a8 = (ch4 & 1) ? xhi : xlo;
      xa0 = MFMA(a8, myz[8 * 64 + lane], xa0, 0, 0, 0);
      xa1 = MFMA(a8, myz[9 * 64 + lane], xa1, 0, 0, 0);
    }

    // in-register GRU update (C rows 0..7 live in ch4<2 lanes)
    if (ch4 < 2) {
#pragma unroll
      for (int i = 0; i < 4; ++i) {
        int row = ch4 * 4 + i;
        {
          float r = sigmoid_f(ra0[i] + bsr0);
          float z = sigmoid_f(za0[i] + bsz0);
          float pre = xa0[i] + bin0 + r * (na0[i] + bhn0);
          float e = __expf(2.f * pre);
          float n = 1.f - __fdividef(2.f, e + 1.f);
          h0[i] = z * h0[i] + (1.f - z) * n;
          int pos = (j0 & ~31) | ((((j0 >> 3) & 3) ^ (row & 3)) << 3) | (j0 & 7);
          wb[row * HROW + pos] = (_Float16)h0[i];
        }
        {
          float r = sigmoid_f(ra1[i] + bsr1);
          float z = sigmoid_f(za1[i] + bsz1);
          float pre = xa1[i] + bin1 + r * (na1[i] + bhn1);
          float e = __expf(2.f * pre);
          float n = 1.f - __fdividef(2.f, e + 1.f);
          h1[i] = z * h1[i] + (1.f - z) * n;
          if (g1ok) {
            int pos = (j1 & ~31) | ((((j1 >> 3) & 3) ^ (row & 3)) << 3) | (j1 & 7);
            wb[row * HROW + pos] = (_Float16)h1[i];
          }
        }
      }
    }
    __syncthreads();
  }

  if (ch4 < 2) {
#pragma unroll
    for (int i = 0; i < 4; ++i) {
      int row = ch4 * 4 + i;
      if (j0 < H) out[(size_t)(blk * RPB + row) * H + j0] = h0[i];
      if (g1ok && j1 < H) out[(size_t)(blk * RPB + row) * H + j1] = h1[i];
    }
  }
}

extern "C" void kernel_launch(void* const* d_in, const int* in_sizes, int n_in,
                              void* d_out, int out_size, void* d_ws, size_t ws_size,
                              hipStream_t stream) {
  const float* X      = (const float*)d_in[0];
  const float* conv_w = (const float*)d_in[1];
  const float* conv_b = (const float*)d_in[2];
  const float* w_ih   = (const float*)d_in[3];
  const float* w_hh   = (const float*)d_in[4];
  const float* b_ih   = (const float*)d_in[5];
  const float* b_hh   = (const float*)d_in[6];
  float* out = (float*)d_out;

  static bool attr_set = false;
  if (!attr_set) {
    hipFuncSetAttribute((const void*)st_gru_kernel,
                        hipFuncAttributeMaxDynamicSharedMemorySize, SMEM_BYTES);
    attr_set = true;
  }

  pack_w_kernel<<<dim3(NT2, NS), 64, 0, stream>>>(w_ih, w_hh);
  st_gru_kernel<<<NBLK, NTHR, SMEM_BYTES, stream>>>(X, conv_w, conv_b, b_ih, b_hh, out);
}

// Round 4
// 183.323 us; speedup vs baseline: 3.0904x; 1.7693x over previous
//
#include <hip/hip_runtime.h>

#define BATCH 2048
#define T     128
#define CIN   2
#define COUT  16
#define H     232
#define RPB   8                 // batch rows per block
#define NBLK  (BATCH/RPB)       // 256 blocks -> 1 per CU
#define NTHR  512               // 8 waves, 2/SIMD
#define NGRP  15                // j-groups of 16 (232 -> 240 padded)
#define NT2   48                // tiles: r=0..14, z=15..29, n=30..44, 45..47 zero pad
#define NS    9                 // K slices of 32
#define HROW  272               // hA row stride in halves

// dynamic LDS carve (bytes)
#define OFF_HA   0
#define SZ_HA    (2 * RPB * HROW * 2)          // 8704: ping-pong fp16 h
#define OFF_XE   (OFF_HA + SZ_HA)
#define SZ_XE    (T * RPB * 16 * 2)            // 32768: conv output all t
#define OFF_WL   (OFF_XE + SZ_XE)
#define SZ_WL    (8 * 10 * 64 * 8 * 2)         // 81920: per-wave z s0..3 + xn frags
#define OFF_CW   (OFF_WL + SZ_WL)
#define SZ_CW    512
#define SMEM_BYTES (OFF_CW + SZ_CW)            // 123904

typedef _Float16 half8 __attribute__((ext_vector_type(8)));
typedef float  floatx4 __attribute__((ext_vector_type(4)));

#define MFMA __builtin_amdgcn_mfma_f32_16x16x32_f16

// packed fp16 weights, fragment-contiguous: [tile][slice][lane][8]
__device__ __align__(16) _Float16 g_packedW[NT2 * NS * 64 * 8];

__global__ void pack_w_kernel(const float* __restrict__ w_ih,
                              const float* __restrict__ w_hh) {
  int tile = blockIdx.x, slice = blockIdx.y, lane = threadIdx.x;
  int grp = tile / NGRP;                       // 0=r,1=z,2=n (3=dummy)
  int j   = (tile % NGRP) * 16 + (lane & 15);
  int g   = grp * H + j;
  bool valid = (tile < 3 * NGRP) && (j < H);
  half8 v = {};
  if (valid) {
#pragma unroll
    for (int i = 0; i < 8; ++i) {
      int k = slice * 32 + ((lane >> 4) << 3) + i;
      float f = 0.f;
      if (slice < 8) {
        if (k < H) f = w_hh[g * H + k];
        else if (k < H + COUT && grp < 2) f = w_ih[g * COUT + (k - H)];
      } else {
        int xk = k - 256;
        if (xk >= 0 && xk < COUT && grp == 2) f = w_ih[g * COUT + xk];
      }
      v[i] = (_Float16)f;
    }
  }
  *(half8*)&g_packedW[((tile * NS + slice) * 64 + lane) * 8] = v;
}

__device__ __forceinline__ float sigmoid_f(float x) {
  return __builtin_amdgcn_rcpf(1.f + __expf(-x));
}

__global__ __launch_bounds__(NTHR, 2) void st_gru_kernel(
    const float* __restrict__ X,
    const float* __restrict__ conv_w, const float* __restrict__ conv_b,
    const float* __restrict__ b_ih, const float* __restrict__ b_hh,
    float* __restrict__ out) {

  extern __shared__ __align__(16) char smem[];
  _Float16* hAflat = (_Float16*)(smem + OFF_HA);
  _Float16* Xemb   = (_Float16*)(smem + OFF_XE);
  _Float16* wLDS   = (_Float16*)(smem + OFF_WL);
  float*    cwp    = (float*)(smem + OFF_CW);

  const int tid  = threadIdx.x;
  const int lane = tid & 63;
  const int wave = tid >> 6;
  const int r_a  = lane & 15;   // A row / C col (gate j within group)
  const int ch4  = lane >> 4;   // k-chunk / C row group
  const int blk  = blockIdx.x;
  const int rr   = r_a & 7;     // batch row this lane reads (rows 8-15 duplicate 0-7)
  const int swz  = rr & 3;

  for (int i = tid; i < 2 * RPB * HROW; i += NTHR) hAflat[i] = (_Float16)0;
  if (tid < COUT * CIN * 3) cwp[tid] = conv_w[tid];
  if (tid < COUT) cwp[96 + tid] = conv_b[tid];
  __syncthreads();

  // ---- conv1d(2->16,k=3,pad=1)+ReLU for ALL t upfront -> Xemb (fp16)
  for (int p = tid; p < RPB * T; p += NTHR) {
    int r = p >> 7, t = p & (T - 1);
    const float* xr = X + (size_t)(blk * RPB + r) * (T * CIN);
    float x0[3], x1[3];
#pragma unroll
    for (int d = 0; d < 3; ++d) {
      int tt = t + d - 1;
      bool ok = (unsigned)tt < (unsigned)T;
      x0[d] = ok ? xr[tt * 2] : 0.f;
      x1[d] = ok ? xr[tt * 2 + 1] : 0.f;
    }
    half8 lo, hi;
#pragma unroll
    for (int c = 0; c < COUT; ++c) {
      float a = cwp[96 + c];
#pragma unroll
      for (int d = 0; d < 3; ++d)
        a += x0[d] * cwp[c * 6 + d] + x1[d] * cwp[c * 6 + 3 + d];
      _Float16 hv = (_Float16)fmaxf(a, 0.f);
      if (c < 8) lo[c] = hv; else hi[c - 8] = hv;
    }
    *(half8*)&Xemb[(t * RPB + r) * 16] = lo;
    *(half8*)&Xemb[(t * RPB + r) * 16 + 8] = hi;
  }

  // ---- per-wave tiles (2 gate-triples each)
  const int gi0 = wave * 2, gi1 = wave * 2 + 1;
  const bool g1ok = (gi1 < NGRP);
  const int tr0 = gi0, tz0 = gi0 + NGRP, tn0 = gi0 + 2 * NGRP;
  const int tr1 = g1ok ? gi1 : 45, tz1 = g1ok ? gi1 + NGRP : 46, tn1 = g1ok ? gi1 + 2 * NGRP : 47;
  const half8* Wp = (const half8*)g_packedW;

  // LDS-staged frags: z s0..3 of both tiles (0..7), x-slice of n for both (8,9)
  half8* myz = (half8*)(wLDS + wave * (10 * 64 * 8));
#pragma unroll
  for (int f = 0; f < 4; ++f) myz[f * 64 + lane] = Wp[(tz0 * NS + f) * 64 + lane];
#pragma unroll
  for (int f = 0; f < 4; ++f) myz[(4 + f) * 64 + lane] = Wp[(tz1 * NS + f) * 64 + lane];
  myz[8 * 64 + lane] = Wp[(tn0 * NS + 8) * 64 + lane];
  myz[9 * 64 + lane] = Wp[(tn1 * NS + 8) * 64 + lane];

  // VGPR/AGPR-resident frags: r s0..7, n s0..7, z s4..7
  half8 wr0[8], wr1[8], wn0[8], wn1[8], wzh0[4], wzh1[4];
#pragma unroll
  for (int s = 0; s < 8; ++s) {
    wr0[s] = Wp[(tr0 * NS + s) * 64 + lane];
    wr1[s] = Wp[(tr1 * NS + s) * 64 + lane];
    wn0[s] = Wp[(tn0 * NS + s) * 64 + lane];
    wn1[s] = Wp[(tn1 * NS + s) * 64 + lane];
  }
#pragma unroll
  for (int s = 0; s < 4; ++s) {
    wzh0[s] = Wp[(tz0 * NS + 4 + s) * 64 + lane];
    wzh1[s] = Wp[(tz1 * NS + 4 + s) * 64 + lane];
  }

  const int j0 = gi0 * 16 + r_a, j1 = gi1 * 16 + r_a;
  float bsr0 = 0.f, bsz0 = 0.f, bin0 = 0.f, bhn0 = 0.f;
  float bsr1 = 0.f, bsz1 = 0.f, bin1 = 0.f, bhn1 = 0.f;
  if (j0 < H) {
    bsr0 = b_ih[j0] + b_hh[j0];
    bsz0 = b_ih[H + j0] + b_hh[H + j0];
    bin0 = b_ih[2 * H + j0]; bhn0 = b_hh[2 * H + j0];
  }
  if (g1ok && j1 < H) {
    bsr1 = b_ih[j1] + b_hh[j1];
    bsz1 = b_ih[H + j1] + b_hh[H + j1];
    bin1 = b_ih[2 * H + j1]; bhn1 = b_hh[2 * H + j1];
  }

  // ---- all-lane update distribution: lanes ch4 0..3 own (elem,row) pairs
  // ch4=0: e{0,1} rows 0,1 | ch4=1: e{0,1} rows 4,5 | ch4=2: e{2,3} rows 2,3 | ch4=3: e{2,3} rows 6,7
  const int eb   = (ch4 & 2);                    // acc element base (0 or 2)
  const int rowb = ((ch4 & 1) << 2) | (ch4 & 2); // batch row base

  // precomputed lane-constant write offsets into the h ping-pong buffer
  int woff0[2], woff1[2];
#pragma unroll
  for (int u = 0; u < 2; ++u) {
    int row = rowb + u;
    woff0[u] = row * HROW + ((j0 & ~31) | ((((j0 >> 3) & 3) ^ (row & 3)) << 3) | (j0 & 7));
    woff1[u] = row * HROW + ((j1 & ~31) | ((((j1 >> 3) & 3) ^ (row & 3)) << 3) | (j1 & 7));
  }

  float h0[2] = {0.f, 0.f};
  float h1[2] = {0.f, 0.f};

  __syncthreads();

  const int abase = rr * HROW + ((ch4 ^ swz) << 3);   // A-frag offset (halves)

  for (int t = 0; t < T; ++t) {
    const _Float16* rb = hAflat + (t & 1) * (RPB * HROW);
    _Float16* wb = hAflat + ((t & 1) ^ 1) * (RPB * HROW);

    // A7 (k 224..255): ch4=0 -> h tail; ch4=1,2 -> x lo/hi; ch4=3 -> any (weights zero)
    const _Float16* pa7 = (ch4 == 0)
        ? rb + rr * HROW + 224 + (swz << 3)
        : Xemb + (t * RPB + rr) * 16 + ((((ch4 - 1) & 1)) << 3);
    half8 A7 = *(const half8*)pa7;
    // A8 (k 256..287): x projection for n-gates; ch4>=2 weights zero
    half8 A8 = *(const half8*)(Xemb + (t * RPB + rr) * 16 + ((ch4 & 1) << 3));

    // ---- triple 0 MFMAs
    floatx4 ra0 = {}, za0 = {}, na0 = {}, xa0 = {};
#pragma unroll
    for (int s = 0; s < 4; ++s) {
      half8 a = *(const half8*)&rb[abase + s * 32];
      ra0 = MFMA(a, wr0[s], ra0, 0, 0, 0);
      za0 = MFMA(a, myz[s * 64 + lane], za0, 0, 0, 0);
      na0 = MFMA(a, wn0[s], na0, 0, 0, 0);
    }
#pragma unroll
    for (int s = 4; s < 7; ++s) {
      half8 a = *(const half8*)&rb[abase + s * 32];
      ra0 = MFMA(a, wr0[s], ra0, 0, 0, 0);
      za0 = MFMA(a, wzh0[s - 4], za0, 0, 0, 0);
      na0 = MFMA(a, wn0[s], na0, 0, 0, 0);
    }
    ra0 = MFMA(A7, wr0[7], ra0, 0, 0, 0);
    za0 = MFMA(A7, wzh0[3], za0, 0, 0, 0);
    na0 = MFMA(A7, wn0[7], na0, 0, 0, 0);   // n-tile k>=232 weights are zero
    xa0 = MFMA(A8, myz[8 * 64 + lane], xa0, 0, 0, 0);

    // ---- triple 1 MFMAs (independent; overlaps update 0 below)
    floatx4 ra1 = {}, za1 = {}, na1 = {}, xa1 = {};
#pragma unroll
    for (int s = 0; s < 4; ++s) {
      half8 a = *(const half8*)&rb[abase + s * 32];
      ra1 = MFMA(a, wr1[s], ra1, 0, 0, 0);
      za1 = MFMA(a, myz[(4 + s) * 64 + lane], za1, 0, 0, 0);
      na1 = MFMA(a, wn1[s], na1, 0, 0, 0);
    }
#pragma unroll
    for (int s = 4; s < 7; ++s) {
      half8 a = *(const half8*)&rb[abase + s * 32];
      ra1 = MFMA(a, wr1[s], ra1, 0, 0, 0);
      za1 = MFMA(a, wzh1[s - 4], za1, 0, 0, 0);
      na1 = MFMA(a, wn1[s], na1, 0, 0, 0);
    }
    ra1 = MFMA(A7, wr1[7], ra1, 0, 0, 0);
    za1 = MFMA(A7, wzh1[3], za1, 0, 0, 0);
    na1 = MFMA(A7, wn1[7], na1, 0, 0, 0);
    xa1 = MFMA(A8, myz[9 * 64 + lane], xa1, 0, 0, 0);

    // ---- update 0 (all 64 lanes useful; overlaps triple-1 matrix work)
#pragma unroll
    for (int u = 0; u < 2; ++u) {
      int e = eb + u;
      float r = sigmoid_f(ra0[e] + bsr0);
      float z = sigmoid_f(za0[e] + bsz0);
      float pre = xa0[e] + bin0 + r * (na0[e] + bhn0);
      float ee = __expf(2.f * pre);
      float n = 1.f - 2.f * __builtin_amdgcn_rcpf(ee + 1.f);
      h0[u] = n + z * (h0[u] - n);
      wb[woff0[u]] = (_Float16)h0[u];          // j0>=H lands in pad slots (value 0)
    }
    // ---- update 1
#pragma unroll
    for (int u = 0; u < 2; ++u) {
      int e = eb + u;
      float r = sigmoid_f(ra1[e] + bsr1);
      float z = sigmoid_f(za1[e] + bsz1);
      float pre = xa1[e] + bin1 + r * (na1[e] + bhn1);
      float ee = __expf(2.f * pre);
      float n = 1.f - 2.f * __builtin_amdgcn_rcpf(ee + 1.f);
      h1[u] = n + z * (h1[u] - n);
      wb[woff1[u]] = (_Float16)h1[u];          // wave 7 writes zeros to pad slots
    }
    __syncthreads();
  }

#pragma unroll
  for (int u = 0; u < 2; ++u) {
    int row = rowb + u;
    if (j0 < H) out[(size_t)(blk * RPB + row) * H + j0] = h0[u];
    if (g1ok && j1 < H) out[(size_t)(blk * RPB + row) * H + j1] = h1[u];
  }
}

extern "C" void kernel_launch(void* const* d_in, const int* in_sizes, int n_in,
                              void* d_out, int out_size, void* d_ws, size_t ws_size,
                              hipStream_t stream) {
  const float* X      = (const float*)d_in[0];
  const float* conv_w = (const float*)d_in[1];
  const float* conv_b = (const float*)d_in[2];
  const float* w_ih   = (const float*)d_in[3];
  const float* w_hh   = (const float*)d_in[4];
  const float* b_ih   = (const float*)d_in[5];
  const float* b_hh   = (const float*)d_in[6];
  float* out = (float*)d_out;

  static bool attr_set = false;
  if (!attr_set) {
    hipFuncSetAttribute((const void*)st_gru_kernel,
                        hipFuncAttributeMaxDynamicSharedMemorySize, SMEM_BYTES);
    attr_set = true;
  }

  pack_w_kernel<<<dim3(NT2, NS), 64, 0, stream>>>(w_ih, w_hh);
  st_gru_kernel<<<NBLK, NTHR, SMEM_BYTES, stream>>>(X, conv_w, conv_b, b_ih, b_hh, out);
}